// Round 6
// baseline (22.288 us; speedup 1.0000x reference)
//
#include <hip/hip_runtime.h>
#include <math.h>

#define HIDDEN 2048
#define IN_F 350

__device__ __forceinline__ float sigmoidf_(float v) { return 1.0f / (1.0f + expf(-v)); }
__device__ __forceinline__ float dot4_(float4 a, float4 b) {
    return a.x*b.x + a.y*b.y + a.z*b.z + a.w*b.w;
}

// K1: feat + LSTM layer 0 (h=c=0 => f-gate dead, W_hh unused).
// 512 blocks x 768 thr (12 waves). Block b owns units [4b,4b+4); wave w ->
// (unit 4b + w/3, gate w%3). feat computed once per block (4x less redundancy),
// extrema fully parallel.
__global__ __launch_bounds__(768) void k1_feat_lstm0(
    const float* __restrict__ x, const float* __restrict__ Wih,
    const float* __restrict__ bih, const float* __restrict__ bhh,
    float* __restrict__ h1)
{
    __shared__ __align__(16) float feat[IN_F];
    __shared__ float hx[84];     // hands, contiguous copy of x[182..265]
    __shared__ float sc[12];     // 4 source points (8) + dl/dr (4)
    __shared__ float ext[4];     // wl, hl, wr, hr
    __shared__ float gd[12];
    const int tid = threadIdx.x, wave = tid >> 6, lane = tid & 63;
    const int b = blockIdx.x;

    if (tid < 84) hx[tid] = x[182 + tid];
    else if (tid < 92) {
        int t = tid - 84;
        int p = t >> 1;                                   // body,face,left,right
        int base = (p == 0) ? 0 : (p == 1) ? 106 : (p == 2) ? 200 : 242;
        sc[t] = x[base + (t & 1)];
    }
    __syncthreads();
    if (tid < 4) {                                        // extrema: (hand, coord)
        const int h = tid >> 1, c = tid & 1;
        float m = hx[h*42 + c], M = m;
        #pragma unroll
        for (int jj = 1; jj < 21; ++jj) {
            float v = hx[h*42 + 2*jj + c];
            m = fminf(m, v); M = fmaxf(M, v);
        }
        ext[tid] = M - m;
    }
    __syncthreads();
    if (tid < 4) {
        const int h = tid >> 1;
        bool ok = (ext[2*h] != 0.0f) && (ext[2*h + 1] != 0.0f);
        sc[8 + tid] = ok ? ext[tid] : 1.0f;
    }
    __syncthreads();
    if (tid < 133) {
        const float sbx = sc[0], sby = sc[1], sfx = sc[2], sfy = sc[3];
        const float slx = sc[4], sly = sc[5], srx = sc[6], sry = sc[7];
        const float dlx = sc[8], dly = sc[9], drx = sc[10], dry = sc[11];
        const int k = tid;
        float vx = x[2*k], vy = x[2*k + 1];
        if (k < 17) {                 // body
            feat[2*k]   = vx - sbx;  feat[2*k+1] = vy - sby;
        } else if (k < 23) {          // feet
            feat[2*k]   = vx;        feat[2*k+1] = vy;
        } else if (k < 91) {          // face
            feat[2*k]   = vx - sfx;  feat[2*k+1] = vy - sfy;
        } else if (k < 112) {         // left hand + chin2l
            int jj = k - 91;
            feat[182 + 2*jj] = (vx - slx) / dlx;  feat[183 + 2*jj] = (vy - sly) / dly;
            feat[266 + 2*jj] = vx - sbx;          feat[267 + 2*jj] = vy - sby;
        } else {                      // right hand + chin2r
            int jj = k - 112;
            feat[224 + 2*jj] = (vx - srx) / drx;  feat[225 + 2*jj] = (vy - sry) / dry;
            feat[308 + 2*jj] = vx - sbx;          feat[309 + 2*jj] = vy - sby;
        }
    }
    __syncthreads();

    // wave w: unit u = 4b + w/3, gate = w%3 -> row {0,2,3}[gate]*H + u
    const int u = b * 4 + wave / 3;
    const int gate = wave % 3;
    const int grow = ((gate == 0) ? 0 : (gate == 1) ? 2 : 3) * HIDDEN + u;
    const float2* wr = (const float2*)(Wih + (size_t)grow * IN_F);
    const float2* f2 = (const float2*)feat;
    const bool has2 = (128 + lane) < 175;
    float2 w0 = wr[lane];
    float2 w1 = wr[64 + lane];
    float2 w2 = has2 ? wr[128 + lane] : make_float2(0.f, 0.f);
    float2 f0 = f2[lane];
    float2 f1 = f2[64 + lane];
    float2 fx = has2 ? f2[128 + lane] : make_float2(0.f, 0.f);
    float acc = w0.x*f0.x + w0.y*f0.y + w1.x*f1.x + w1.y*f1.y + w2.x*fx.x + w2.y*fx.y;
    #pragma unroll
    for (int off = 32; off; off >>= 1) acc += __shfl_down(acc, off);
    if (lane == 0) gd[wave] = acc + bih[grow] + bhh[grow];
    __syncthreads();
    if (tid < 4) {
        float c = sigmoidf_(gd[3*tid + 0]) * tanhf(gd[3*tid + 1]);
        h1[b*4 + tid] = sigmoidf_(gd[3*tid + 2]) * tanhf(c);
    }
}

// K2: LSTM layer 1 (h=c=0 again). 1024 blocks x 384 thr (6 waves).
// Block b owns units {2b, 2b+1}; wave w -> (unit 2b + (w>=3), gate w%3).
// h1 staged once into LDS (8 KB) -> global traffic is the weight stream only.
// 4 blocks/CU x 6 waves = 24 waves/CU.
__global__ __launch_bounds__(384) void k2_lstm1(
    const float* __restrict__ Wih, const float* __restrict__ bih,
    const float* __restrict__ bhh, const float* __restrict__ h1,
    float* __restrict__ h2)
{
    __shared__ __align__(16) float h1s[HIDDEN];
    __shared__ float gd[6];
    const int tid = threadIdx.x, wave = tid >> 6, lane = tid & 63;
    const int b = blockIdx.x;

    {   // stage h1: 512 float4 over 384 threads
        const float4* h4g = (const float4*)h1;
        float4* h4s = (float4*)h1s;
        h4s[tid] = h4g[tid];
        if (tid < 128) h4s[384 + tid] = h4g[384 + tid];
    }
    __syncthreads();

    const int u = b * 2 + (wave >= 3 ? 1 : 0);
    const int gate = wave % 3;
    const int grow = ((gate == 0) ? 0 : (gate == 1) ? 2 : 3) * HIDDEN + u;
    const float4* wr = (const float4*)(Wih + (size_t)grow * HIDDEN);
    const float4* h4 = (const float4*)h1s;

    float4 wv0 = wr[lane];
    float4 wv1 = wr[ 64 + lane];
    float4 wv2 = wr[128 + lane];
    float4 wv3 = wr[192 + lane];
    float4 wv4 = wr[256 + lane];
    float4 wv5 = wr[320 + lane];
    float4 wv6 = wr[384 + lane];
    float4 wv7 = wr[448 + lane];

    float acc = dot4_(wv0, h4[lane])       + dot4_(wv1, h4[ 64 + lane])
              + dot4_(wv2, h4[128 + lane]) + dot4_(wv3, h4[192 + lane])
              + dot4_(wv4, h4[256 + lane]) + dot4_(wv5, h4[320 + lane])
              + dot4_(wv6, h4[384 + lane]) + dot4_(wv7, h4[448 + lane]);
    #pragma unroll
    for (int off = 32; off; off >>= 1) acc += __shfl_down(acc, off);
    if (lane == 0) gd[wave] = acc + bih[grow] + bhh[grow];
    __syncthreads();
    if (tid < 2) {
        float c = sigmoidf_(gd[3*tid + 0]) * tanhf(gd[3*tid + 1]);
        h2[b*2 + tid] = sigmoidf_(gd[3*tid + 2]) * tanhf(c);
    }
}

// K3: out[r] = fc_w[r,:] . h2 + fc_b[r]. 350 blocks x 256 thr (4 waves, K-split).
__global__ __launch_bounds__(256) void k3_fc(
    const float* __restrict__ h2, const float* __restrict__ W,
    const float* __restrict__ b, float* __restrict__ out)
{
    __shared__ float part[4];
    const int tid = threadIdx.x, wave = tid >> 6, lane = tid & 63;
    const int r = blockIdx.x;
    const float4* wr = (const float4*)(W + (size_t)r * HIDDEN);
    const float4* h4 = (const float4*)h2;
    const int base = wave * 128;              // 512 float4 / 4 waves
    float4 w0 = wr[base + lane], w1 = wr[base + 64 + lane];
    float4 v0 = h4[base + lane], v1 = h4[base + 64 + lane];
    float acc = dot4_(w0, v0) + dot4_(w1, v1);
    #pragma unroll
    for (int off = 32; off; off >>= 1) acc += __shfl_down(acc, off);
    if (lane == 0) part[wave] = acc;
    __syncthreads();
    if (tid == 0) out[r] = part[0] + part[1] + part[2] + part[3] + b[r];
}

extern "C" void kernel_launch(void* const* d_in, const int* in_sizes, int n_in,
                              void* d_out, int out_size, void* d_ws, size_t ws_size,
                              hipStream_t stream) {
    const float* x     = (const float*)d_in[0];
    const float* W_ih0 = (const float*)d_in[1];
    // d_in[2] = W_hh0 : unused (h0 == 0)
    const float* b_ih0 = (const float*)d_in[3];
    const float* b_hh0 = (const float*)d_in[4];
    const float* W_ih1 = (const float*)d_in[5];
    // d_in[6] = W_hh1 : unused (h == 0 for cell 2 as well)
    const float* b_ih1 = (const float*)d_in[7];
    const float* b_hh1 = (const float*)d_in[8];
    const float* fc_w  = (const float*)d_in[9];
    const float* fc_b  = (const float*)d_in[10];

    float* h1 = (float*)d_ws;            // 2048 floats
    float* h2 = (float*)d_ws + HIDDEN;   // 2048 floats

    k1_feat_lstm0<<<512, 768, 0, stream>>>(x, W_ih0, b_ih0, b_hh0, h1);
    k2_lstm1<<<1024, 384, 0, stream>>>(W_ih1, b_ih1, b_hh1, h1, h2);
    k3_fc<<<IN_F, 256, 0, stream>>>(h2, fc_w, fc_b, (float*)d_out);
}